// Round 1
// baseline (1052.778 us; speedup 1.0000x reference)
//
#include <hip/hip_runtime.h>

#define DIM 4096
#define SEQ 2048
#define NH 32
#define HD 128

typedef __bf16 bf16x8 __attribute__((ext_vector_type(8)));
typedef float f32x4 __attribute__((ext_vector_type(4)));

__device__ inline ushort f2bf(float f) {
    union { float f; unsigned u; } v; v.f = f;
    unsigned r = v.u + 0x7fffu + ((v.u >> 16) & 1u);
    return (ushort)(r >> 16);
}
__device__ inline float bf2f(ushort h) {
    union { unsigned u; float f; } v; v.u = ((unsigned)h) << 16;
    return v.f;
}

// ---------------- fp32 -> bf16 convert (vectorized) ----------------
__global__ void f2b_kernel(const float* __restrict__ in, ushort* __restrict__ out, int n4) {
    int i = blockIdx.x * blockDim.x + threadIdx.x;
    if (i < n4) {
        float4 v = ((const float4*)in)[i];
        ushort4 o;
        o.x = f2bf(v.x); o.y = f2bf(v.y); o.z = f2bf(v.z); o.w = f2bf(v.w);
        ((ushort4*)out)[i] = o;
    }
}

// ---------------- degenerate rotary: elementwise scale on q,k ----------------
// out[s,h,d] = in[s,h,d] * (cos(a[s,d>>1]) + (d&1 ? +sin : -sin)(a[s,d>>1]))
__global__ void rotary_kernel(ushort* __restrict__ q, ushort* __restrict__ k,
                              const float* __restrict__ freqs) {
    int idx = blockIdx.x * blockDim.x + threadIdx.x;  // over SEQ*DIM
    int s = idx >> 12;
    int d = idx & 127;
    int dh = d >> 1;
    float cs = freqs[(s * 64 + dh) * 2 + 0];
    float sn = freqs[(s * 64 + dh) * 2 + 1];
    float f = (d & 1) ? (cs + sn) : (cs - sn);
    q[idx] = f2bf(bf2f(q[idx]) * f);
    k[idx] = f2bf(bf2f(k[idx]) * f);
}

// ---------------- bf16 GEMM: C[m][n] = sum_k A[m][k] * B[n][k] ----------------
// m97-style: 128x128 tile, BK=32, 4 waves (2x2), each wave 4x4 MFMA 16x16x32 tiles,
// global_load_lds width=16 staging (LDS layout must be lane-contiguous, no padding).
template <int BF16OUT>
__global__ __launch_bounds__(256)
void gemm_bt(const ushort* __restrict__ A, const ushort* __restrict__ B,
             void* __restrict__ C, int M, int N, int K) {
    __shared__ __align__(16) ushort sA[128 * 32];
    __shared__ __align__(16) ushort sB[128 * 32];
    const int tid  = threadIdx.x;
    const int wave = tid >> 6, lane = tid & 63;
    const int quad = lane >> 4, c = lane & 15;
    const int m0 = blockIdx.y * 128, n0 = blockIdx.x * 128;
    const int wm = (wave >> 1) * 64, wn = (wave & 1) * 64;

    const f32x4 vzero = {0.f, 0.f, 0.f, 0.f};
    f32x4 acc[4][4];
#pragma unroll
    for (int i = 0; i < 4; i++)
#pragma unroll
        for (int j = 0; j < 4; j++) acc[i][j] = vzero;

    const int srow = lane >> 2;        // 0..15
    const int scol = (lane & 3) * 8;   // 0,8,16,24
    const size_t arow0 = (size_t)(m0 + wave * 32) * K;
    const size_t brow0 = (size_t)(n0 + wave * 32) * K;

    for (int k0 = 0; k0 < K; k0 += 32) {
#pragma unroll
        for (int j = 0; j < 2; j++) {
            __builtin_amdgcn_global_load_lds(
                (const __attribute__((address_space(1))) void*)(A + arow0 + (size_t)(j * 16 + srow) * K + k0 + scol),
                (__attribute__((address_space(3))) void*)(&sA[(wave * 32 + j * 16) * 32]), 16, 0, 0);
            __builtin_amdgcn_global_load_lds(
                (const __attribute__((address_space(1))) void*)(B + brow0 + (size_t)(j * 16 + srow) * K + k0 + scol),
                (__attribute__((address_space(3))) void*)(&sB[(wave * 32 + j * 16) * 32]), 16, 0, 0);
        }
        __syncthreads();
        bf16x8 af[4], bfr[4];
#pragma unroll
        for (int t = 0; t < 4; t++) {
            af[t]  = *(const bf16x8*)&sA[(wm + t * 16 + c) * 32 + quad * 8];
            bfr[t] = *(const bf16x8*)&sB[(wn + t * 16 + c) * 32 + quad * 8];
        }
#pragma unroll
        for (int mt = 0; mt < 4; mt++)
#pragma unroll
            for (int nt = 0; nt < 4; nt++)
                acc[mt][nt] = __builtin_amdgcn_mfma_f32_16x16x32_bf16(af[mt], bfr[nt], acc[mt][nt], 0, 0, 0);
        __syncthreads();
    }

    // epilogue: C/D layout col=lane&15, row=quad*4+reg (m89-verified)
#pragma unroll
    for (int mt = 0; mt < 4; mt++) {
#pragma unroll
        for (int nt = 0; nt < 4; nt++) {
#pragma unroll
            for (int r = 0; r < 4; r++) {
                int row = m0 + wm + mt * 16 + quad * 4 + r;
                int col = n0 + wn + nt * 16 + c;
                float v = acc[mt][nt][r];
                if (BF16OUT)
                    ((ushort*)C)[(size_t)row * N + col] = f2bf(v);
                else
                    ((float*)C)[(size_t)row * N + col] = v;
            }
        }
    }
}

// ---------------- flash attention (causal), bf16 MFMA ----------------
// Block: 4 waves, BQ=64 (wave w owns q rows q0+w*16..+15), K-tiles of 64 keys.
__global__ __launch_bounds__(256)
void flash_kernel(const ushort* __restrict__ Q, const ushort* __restrict__ K,
                  const ushort* __restrict__ V, ushort* __restrict__ O) {
    const int h  = blockIdx.x;
    const int qb = blockIdx.y;
    __shared__ __align__(16) ushort sK[64 * 136];    // K-tile [key][d], padded (+8)
    __shared__ __align__(16) ushort sVt[128 * 72];   // V-tile transposed [d][key], padded (+8)
    __shared__ __align__(16) ushort sP[4][16 * 72];  // per-wave P [qrow][key], padded (+8)
    const int tid = threadIdx.x, wave = tid >> 6, lane = tid & 63;
    const int quad = lane >> 4, c = lane & 15;
    const int q0 = qb * 64;
    const float scale = 0.08838834764831845f;  // 1/sqrt(128)

    // preload Q fragments (A-layout: m=lane&15, k=quad*8+j), reused across all K-tiles
    bf16x8 qf[4];
    {
        const ushort* Qp = Q + (size_t)(q0 + wave * 16 + c) * DIM + h * HD;
#pragma unroll
        for (int ks = 0; ks < 4; ks++) qf[ks] = *(const bf16x8*)(Qp + ks * 32 + quad * 8);
    }

    const f32x4 vzero = {0.f, 0.f, 0.f, 0.f};
    f32x4 oa[8];
#pragma unroll
    for (int dt = 0; dt < 8; dt++) oa[dt] = vzero;
    float ms[4], ls[4];
#pragma unroll
    for (int r = 0; r < 4; r++) { ms[r] = -1e30f; ls[r] = 0.f; }

    for (int kt = 0; kt <= qb; kt++) {
        __syncthreads();  // protect LDS reuse from previous iteration's readers
        // stage K [64][128] and V^T [128][64] (coalesced 8B global reads)
#pragma unroll
        for (int i = 0; i < 8; i++) {
            int g = tid + i * 256;
            int key = g >> 5, d4 = (g & 31) * 4;
            const size_t gofs = (size_t)(kt * 64 + key) * DIM + h * HD + d4;
            uint2 kv = *(const uint2*)(K + gofs);
            *(uint2*)&sK[key * 136 + d4] = kv;
            ushort4 vv = *(const ushort4*)(V + gofs);
            sVt[(d4 + 0) * 72 + key] = vv.x;
            sVt[(d4 + 1) * 72 + key] = vv.y;
            sVt[(d4 + 2) * 72 + key] = vv.z;
            sVt[(d4 + 3) * 72 + key] = vv.w;
        }
        __syncthreads();

        // S = Q K^T  (4 n-tiles of keys x 4 k-steps over d)
        f32x4 s[4];
#pragma unroll
        for (int nt = 0; nt < 4; nt++) s[nt] = vzero;
#pragma unroll
        for (int ks = 0; ks < 4; ks++)
#pragma unroll
            for (int nt = 0; nt < 4; nt++) {
                bf16x8 kf = *(const bf16x8*)&sK[(nt * 16 + c) * 136 + ks * 32 + quad * 8];
                s[nt] = __builtin_amdgcn_mfma_f32_16x16x32_bf16(qf[ks], kf, s[nt], 0, 0, 0);
            }

        // scale + causal mask (only the diagonal tile needs it)
        const bool diag = (kt == qb);
#pragma unroll
        for (int nt = 0; nt < 4; nt++)
#pragma unroll
            for (int r = 0; r < 4; r++) {
                float v = s[nt][r] * scale;
                if (diag) {
                    int keyg = kt * 64 + nt * 16 + c;
                    int qg   = q0 + wave * 16 + quad * 4 + r;
                    if (keyg > qg) v = -1e9f;
                }
                s[nt][r] = v;
            }

        // online softmax: rows quad*4+r live on the quad's 16 lanes
        float mnew[4], alpha[4];
#pragma unroll
        for (int r = 0; r < 4; r++) {
            float v = fmaxf(fmaxf(s[0][r], s[1][r]), fmaxf(s[2][r], s[3][r]));
            v = fmaxf(v, __shfl_xor(v, 1));
            v = fmaxf(v, __shfl_xor(v, 2));
            v = fmaxf(v, __shfl_xor(v, 4));
            v = fmaxf(v, __shfl_xor(v, 8));
            mnew[r]  = fmaxf(ms[r], v);
            alpha[r] = __expf(ms[r] - mnew[r]);
            ms[r]    = mnew[r];
        }
        float rs[4] = {0.f, 0.f, 0.f, 0.f};
#pragma unroll
        for (int nt = 0; nt < 4; nt++)
#pragma unroll
            for (int r = 0; r < 4; r++) {
                float p = __expf(s[nt][r] - mnew[r]);
                rs[r] += p;
                sP[wave][(quad * 4 + r) * 72 + nt * 16 + c] = f2bf(p);
            }
#pragma unroll
        for (int r = 0; r < 4; r++) {
            float v = rs[r];
            v += __shfl_xor(v, 1);
            v += __shfl_xor(v, 2);
            v += __shfl_xor(v, 4);
            v += __shfl_xor(v, 8);
            ls[r] = ls[r] * alpha[r] + v;
        }
#pragma unroll
        for (int dt = 0; dt < 8; dt++)
#pragma unroll
            for (int r = 0; r < 4; r++) oa[dt][r] *= alpha[r];

        // wave-private LDS round-trip for P (C-layout -> A-layout); drain LDS writes
        __asm__ volatile("s_waitcnt lgkmcnt(0)" ::: "memory");

        // O += P V  (8 d-tiles x 2 k-steps over keys)
#pragma unroll
        for (int k2 = 0; k2 < 2; k2++) {
            bf16x8 pf = *(const bf16x8*)&sP[wave][c * 72 + k2 * 32 + quad * 8];
#pragma unroll
            for (int dt = 0; dt < 8; dt++) {
                bf16x8 vf = *(const bf16x8*)&sVt[(dt * 16 + c) * 72 + k2 * 32 + quad * 8];
                oa[dt] = __builtin_amdgcn_mfma_f32_16x16x32_bf16(pf, vf, oa[dt], 0, 0, 0);
            }
        }
    }

    // epilogue: normalize and store bf16 [s][h*128+d]
#pragma unroll
    for (int r = 0; r < 4; r++) {
        float inv = 1.f / ls[r];
        int row = q0 + wave * 16 + quad * 4 + r;
#pragma unroll
        for (int dt = 0; dt < 8; dt++) {
            O[(size_t)row * DIM + h * HD + dt * 16 + c] = f2bf(oa[dt][r] * inv);
        }
    }
}

extern "C" void kernel_launch(void* const* d_in, const int* in_sizes, int n_in,
                              void* d_out, int out_size, void* d_ws, size_t ws_size,
                              hipStream_t stream) {
    const float* x     = (const float*)d_in[0];
    // d_in[1] = start_pos (0), d_in[3] = mask (causal -1e9 triu, applied analytically)
    const float* freqs = (const float*)d_in[2];
    const float* wq    = (const float*)d_in[4];
    const float* wk    = (const float*)d_in[5];
    const float* wv    = (const float*)d_in[6];
    const float* wo    = (const float*)d_in[7];
    float* out = (float*)d_out;

    // workspace layout (bf16 ushort elements), ~218 MB total
    ushort* xb  = (ushort*)d_ws;
    ushort* wqb = xb  + (size_t)SEQ * DIM;
    ushort* wkb = wqb + (size_t)DIM * DIM;
    ushort* wvb = wkb + (size_t)DIM * DIM;
    ushort* wob = wvb + (size_t)DIM * DIM;
    ushort* qb  = wob + (size_t)DIM * DIM;
    ushort* kb  = qb  + (size_t)SEQ * DIM;
    ushort* vb  = kb  + (size_t)SEQ * DIM;
    ushort* ob  = vb  + (size_t)SEQ * DIM;

    const int n4x = SEQ * DIM / 4;
    const int n4w = DIM * DIM / 4;
    f2b_kernel<<<n4x / 256, 256, 0, stream>>>(x,  xb,  n4x);
    f2b_kernel<<<n4w / 256, 256, 0, stream>>>(wq, wqb, n4w);
    f2b_kernel<<<n4w / 256, 256, 0, stream>>>(wk, wkb, n4w);
    f2b_kernel<<<n4w / 256, 256, 0, stream>>>(wv, wvb, n4w);
    f2b_kernel<<<n4w / 256, 256, 0, stream>>>(wo, wob, n4w);

    dim3 gg(DIM / 128, SEQ / 128);
    gemm_bt<1><<<gg, 256, 0, stream>>>(xb, wqb, qb, SEQ, DIM, DIM);
    gemm_bt<1><<<gg, 256, 0, stream>>>(xb, wkb, kb, SEQ, DIM, DIM);
    gemm_bt<1><<<gg, 256, 0, stream>>>(xb, wvb, vb, SEQ, DIM, DIM);

    rotary_kernel<<<SEQ * DIM / 256, 256, 0, stream>>>(qb, kb, freqs);

    flash_kernel<<<dim3(NH, SEQ / 64), 256, 0, stream>>>(qb, kb, vb, ob);

    gemm_bt<0><<<gg, 256, 0, stream>>>(ob, wob, out, SEQ, DIM, DIM);
}

// Round 2
// 812.084 us; speedup vs baseline: 1.2964x; 1.2964x over previous
//
#include <hip/hip_runtime.h>

#define DIM 4096
#define SEQ 2048
#define NH 32
#define HD 128

typedef __bf16 bf16x8 __attribute__((ext_vector_type(8)));
typedef float f32x4 __attribute__((ext_vector_type(4)));

// log2(e) / sqrt(HD): folded into Q so softmax runs in exp2 domain
#define QSCALE 0.12751649736765598f

__device__ inline ushort f2bf(float f) {
    union { float f; unsigned u; } v; v.f = f;
    unsigned r = v.u + 0x7fffu + ((v.u >> 16) & 1u);
    return (ushort)(r >> 16);
}

// ---------------- fused fp32 -> bf16 convert for x + all 4 weights ----------------
__global__ void conv_all(const float* __restrict__ x,  const float* __restrict__ wq,
                         const float* __restrict__ wk, const float* __restrict__ wv,
                         const float* __restrict__ wo,
                         ushort* __restrict__ xb,  ushort* __restrict__ wqb,
                         ushort* __restrict__ wkb, ushort* __restrict__ wvb,
                         ushort* __restrict__ wob) {
    int i = blockIdx.x * 256 + threadIdx.x;   // over (SEQ*DIM + 4*DIM*DIM)/4 float4s
    const float* src; ushort* dst; int off;
    const int n4x = (SEQ * DIM) / 4;          // 2^21
    if (i < n4x) { src = x; dst = xb; off = i; }
    else {
        int j = i - n4x;
        int w = j >> 22;                      // DIM*DIM/4 = 2^22
        off = j & ((1 << 22) - 1);
        src = (w == 0) ? wq : (w == 1) ? wk : (w == 2) ? wv : wo;
        dst = (w == 0) ? wqb : (w == 1) ? wkb : (w == 2) ? wvb : wob;
    }
    float4 v = ((const float4*)src)[off];
    ushort4 o;
    o.x = f2bf(v.x); o.y = f2bf(v.y); o.z = f2bf(v.z); o.w = f2bf(v.w);
    ((ushort4*)dst)[off] = o;
}

// ---------------- fused QKV GEMM, rotary folded into epilogue ----------------
// C[m][n] = sum_k A[m][k] * B[n][k].  Grid (96,16): n-block selects wq/wk/wv.
// Q,K outputs get rotary factor (Q also * QSCALE); V is written TRANSPOSED into
// vt[cv][seq] via ushort4 (4 consecutive seq rows live in one lane's acc regs).
__global__ __launch_bounds__(256)
void gemm_qkv(const ushort* __restrict__ A,
              const ushort* __restrict__ Bq, const ushort* __restrict__ Bk,
              const ushort* __restrict__ Bv,
              ushort* __restrict__ qout, ushort* __restrict__ kout,
              ushort* __restrict__ vt, const float* __restrict__ freqs) {
    __shared__ __align__(16) ushort sA[128 * 32];
    __shared__ __align__(16) ushort sB[128 * 32];
    const int tid = threadIdx.x;
    const int wave = tid >> 6, lane = tid & 63;
    const int quad = lane >> 4, c = lane & 15;
    const int n0g = blockIdx.x * 128;
    const int wsel = n0g >> 12;              // 0=q 1=k 2=v
    const int nloc = n0g & 4095;
    const int m0 = blockIdx.y * 128;
    const int wm = (wave >> 1) * 64, wn = (wave & 1) * 64;
    const ushort* B = (wsel == 0) ? Bq : (wsel == 1) ? Bk : Bv;
    const int K = DIM;

    const f32x4 vzero = {0.f, 0.f, 0.f, 0.f};
    f32x4 acc[4][4];
#pragma unroll
    for (int i = 0; i < 4; i++)
#pragma unroll
        for (int j = 0; j < 4; j++) acc[i][j] = vzero;

    const int srow = lane >> 2;
    const int scol = (lane & 3) * 8;
    const size_t arow0 = (size_t)(m0 + wave * 32) * K;
    const size_t brow0 = (size_t)(nloc + wave * 32) * K;

    for (int k0 = 0; k0 < K; k0 += 32) {
#pragma unroll
        for (int j = 0; j < 2; j++) {
            __builtin_amdgcn_global_load_lds(
                (const __attribute__((address_space(1))) void*)(A + arow0 + (size_t)(j * 16 + srow) * K + k0 + scol),
                (__attribute__((address_space(3))) void*)(&sA[(wave * 32 + j * 16) * 32]), 16, 0, 0);
            __builtin_amdgcn_global_load_lds(
                (const __attribute__((address_space(1))) void*)(B + brow0 + (size_t)(j * 16 + srow) * K + k0 + scol),
                (__attribute__((address_space(3))) void*)(&sB[(wave * 32 + j * 16) * 32]), 16, 0, 0);
        }
        __syncthreads();
        bf16x8 af[4], bfr[4];
#pragma unroll
        for (int t = 0; t < 4; t++) {
            af[t]  = *(const bf16x8*)&sA[(wm + t * 16 + c) * 32 + quad * 8];
            bfr[t] = *(const bf16x8*)&sB[(wn + t * 16 + c) * 32 + quad * 8];
        }
#pragma unroll
        for (int mt = 0; mt < 4; mt++)
#pragma unroll
            for (int nt = 0; nt < 4; nt++)
                acc[mt][nt] = __builtin_amdgcn_mfma_f32_16x16x32_bf16(af[mt], bfr[nt], acc[mt][nt], 0, 0, 0);
        __syncthreads();
    }

    if (wsel < 2) {
        ushort* Cw = wsel ? kout : qout;
        const float qs = wsel ? 1.0f : QSCALE;
#pragma unroll
        for (int mt = 0; mt < 4; mt++) {
#pragma unroll
            for (int nt = 0; nt < 4; nt++) {
                int colg = nloc + wn + nt * 16 + c;
                int dh = (colg & 127) >> 1;
#pragma unroll
                for (int r = 0; r < 4; r++) {
                    int row = m0 + wm + mt * 16 + quad * 4 + r;
                    float2 f2 = ((const float2*)freqs)[row * 64 + dh];
                    float f = (f2.x + ((c & 1) ? f2.y : -f2.y)) * qs;
                    Cw[(size_t)row * DIM + colg] = f2bf(acc[mt][nt][r] * f);
                }
            }
        }
    } else {
        // V: write transposed vt[cv][seq]; lane holds 4 consecutive seq rows
#pragma unroll
        for (int mt = 0; mt < 4; mt++) {
#pragma unroll
            for (int nt = 0; nt < 4; nt++) {
                int cv = nloc + wn + nt * 16 + c;
                int row0 = m0 + wm + mt * 16 + quad * 4;
                ushort4 o;
                o.x = f2bf(acc[mt][nt][0]); o.y = f2bf(acc[mt][nt][1]);
                o.z = f2bf(acc[mt][nt][2]); o.w = f2bf(acc[mt][nt][3]);
                *(ushort4*)&vt[(size_t)cv * SEQ + row0] = o;
            }
        }
    }
}

// ---------------- plain bf16 GEMM with fp32 output (final projection) ----------------
__global__ __launch_bounds__(256)
void gemm_f32out(const ushort* __restrict__ A, const ushort* __restrict__ B,
                 float* __restrict__ C, int M, int N, int K) {
    __shared__ __align__(16) ushort sA[128 * 32];
    __shared__ __align__(16) ushort sB[128 * 32];
    const int tid = threadIdx.x;
    const int wave = tid >> 6, lane = tid & 63;
    const int quad = lane >> 4, c = lane & 15;
    const int m0 = blockIdx.y * 128, n0 = blockIdx.x * 128;
    const int wm = (wave >> 1) * 64, wn = (wave & 1) * 64;

    const f32x4 vzero = {0.f, 0.f, 0.f, 0.f};
    f32x4 acc[4][4];
#pragma unroll
    for (int i = 0; i < 4; i++)
#pragma unroll
        for (int j = 0; j < 4; j++) acc[i][j] = vzero;

    const int srow = lane >> 2;
    const int scol = (lane & 3) * 8;
    const size_t arow0 = (size_t)(m0 + wave * 32) * K;
    const size_t brow0 = (size_t)(n0 + wave * 32) * K;

    for (int k0 = 0; k0 < K; k0 += 32) {
#pragma unroll
        for (int j = 0; j < 2; j++) {
            __builtin_amdgcn_global_load_lds(
                (const __attribute__((address_space(1))) void*)(A + arow0 + (size_t)(j * 16 + srow) * K + k0 + scol),
                (__attribute__((address_space(3))) void*)(&sA[(wave * 32 + j * 16) * 32]), 16, 0, 0);
            __builtin_amdgcn_global_load_lds(
                (const __attribute__((address_space(1))) void*)(B + brow0 + (size_t)(j * 16 + srow) * K + k0 + scol),
                (__attribute__((address_space(3))) void*)(&sB[(wave * 32 + j * 16) * 32]), 16, 0, 0);
        }
        __syncthreads();
        bf16x8 af[4], bfr[4];
#pragma unroll
        for (int t = 0; t < 4; t++) {
            af[t]  = *(const bf16x8*)&sA[(wm + t * 16 + c) * 32 + quad * 8];
            bfr[t] = *(const bf16x8*)&sB[(wn + t * 16 + c) * 32 + quad * 8];
        }
#pragma unroll
        for (int mt = 0; mt < 4; mt++)
#pragma unroll
            for (int nt = 0; nt < 4; nt++)
                acc[mt][nt] = __builtin_amdgcn_mfma_f32_16x16x32_bf16(af[mt], bfr[nt], acc[mt][nt], 0, 0, 0);
        __syncthreads();
    }

#pragma unroll
    for (int mt = 0; mt < 4; mt++)
#pragma unroll
        for (int nt = 0; nt < 4; nt++)
#pragma unroll
            for (int r = 0; r < 4; r++) {
                int row = m0 + wm + mt * 16 + quad * 4 + r;
                int col = n0 + wn + nt * 16 + c;
                C[(size_t)row * N + col] = acc[mt][nt][r];
            }
}

// ---------------- flash attention (causal), balanced pairing + swizzled LDS ----------------
// 512 blocks: block handles head h = bi&31 and q-block pair {p, 31-p}, p = bi>>5
// -> exactly 33 K-tile iterations per block (perfect balance).
// K staged [key][d] and V^T staged [d][key] via global_load_lds w/ XOR chunk swizzle
// (position ch holds global chunk (ch&8)|((ch^row)&7)) -> conflict-free b128 reads.
__global__ __launch_bounds__(256)
void flash_kernel(const ushort* __restrict__ Q, const ushort* __restrict__ K,
                  const ushort* __restrict__ Vt, ushort* __restrict__ O) {
    const int bi = blockIdx.x;
    const int h = bi & (NH - 1);
    const int p = bi >> 5;
    __shared__ __align__(16) ushort sK[64 * 128];
    __shared__ __align__(16) ushort sVt[128 * 64];
    __shared__ __align__(16) ushort sP[4][16 * 72];
    const int tid = threadIdx.x, wave = tid >> 6, lane = tid & 63;
    const int quad = lane >> 4, c = lane & 15;

    for (int pass = 0; pass < 2; pass++) {
        const int qb = pass ? (SEQ / 64 - 1 - p) : p;
        const int q0 = qb * 64;

        bf16x8 qf[4];
        {
            const ushort* Qp = Q + (size_t)(q0 + wave * 16 + c) * DIM + h * HD;
#pragma unroll
            for (int ks = 0; ks < 4; ks++) qf[ks] = *(const bf16x8*)(Qp + ks * 32 + quad * 8);
        }
        const f32x4 vzero = {0.f, 0.f, 0.f, 0.f};
        f32x4 oa[8];
#pragma unroll
        for (int dt = 0; dt < 8; dt++) oa[dt] = vzero;
        float ms[4], ls[4];
#pragma unroll
        for (int r = 0; r < 4; r++) { ms[r] = -1e30f; ls[r] = 0.f; }

        for (int kt = 0; kt <= qb; kt++) {
            __syncthreads();
            // stage K tile [64 keys][128 d]: wave covers 16 rows in 4 insts
#pragma unroll
            for (int i = 0; i < 4; i++) {
                int lr = wave * 16 + i * 4 + (lane >> 4);
                int ch = lane & 15;
                int g = (ch & 8) | ((ch ^ lr) & 7);
                __builtin_amdgcn_global_load_lds(
                    (const __attribute__((address_space(1))) void*)(K + (size_t)(kt * 64 + lr) * DIM + h * HD + g * 8),
                    (__attribute__((address_space(3))) void*)(&sK[(wave * 16 + i * 4) * 128]), 16, 0, 0);
            }
            // stage V^T tile [128 d][64 keys]: wave covers 32 rows in 4 insts
#pragma unroll
            for (int i = 0; i < 4; i++) {
                int ld = wave * 32 + i * 8 + (lane >> 3);
                int ch = lane & 7;
                int g = (ch ^ ld) & 7;
                __builtin_amdgcn_global_load_lds(
                    (const __attribute__((address_space(1))) void*)(Vt + (size_t)(h * HD + ld) * SEQ + kt * 64 + g * 8),
                    (__attribute__((address_space(3))) void*)(&sVt[(wave * 32 + i * 8) * 64]), 16, 0, 0);
            }
            __syncthreads();

            // S = Q K^T (Q pre-scaled by log2e/sqrt(HD))
            f32x4 s[4];
#pragma unroll
            for (int nt = 0; nt < 4; nt++) s[nt] = vzero;
#pragma unroll
            for (int ks = 0; ks < 4; ks++)
#pragma unroll
                for (int nt = 0; nt < 4; nt++) {
                    int lr = nt * 16 + c;
                    int gc = ks * 4 + quad;
                    int pch = (gc & 8) | ((gc ^ lr) & 7);
                    bf16x8 kf = *(const bf16x8*)&sK[lr * 128 + pch * 8];
                    s[nt] = __builtin_amdgcn_mfma_f32_16x16x32_bf16(qf[ks], kf, s[nt], 0, 0, 0);
                }

            if (kt == qb) {  // causal mask on the diagonal tile
#pragma unroll
                for (int nt = 0; nt < 4; nt++)
#pragma unroll
                    for (int r = 0; r < 4; r++) {
                        int keyg = nt * 16 + c;
                        int qg   = wave * 16 + quad * 4 + r;
                        if (keyg > qg) s[nt][r] = -1e30f;
                    }
            }

            // online softmax (exp2 domain)
            float mnew[4], alpha[4];
#pragma unroll
            for (int r = 0; r < 4; r++) {
                float v = fmaxf(fmaxf(s[0][r], s[1][r]), fmaxf(s[2][r], s[3][r]));
                v = fmaxf(v, __shfl_xor(v, 1));
                v = fmaxf(v, __shfl_xor(v, 2));
                v = fmaxf(v, __shfl_xor(v, 4));
                v = fmaxf(v, __shfl_xor(v, 8));
                mnew[r]  = fmaxf(ms[r], v);
                alpha[r] = exp2f(ms[r] - mnew[r]);
                ms[r]    = mnew[r];
            }
            float rs[4] = {0.f, 0.f, 0.f, 0.f};
#pragma unroll
            for (int nt = 0; nt < 4; nt++)
#pragma unroll
                for (int r = 0; r < 4; r++) {
                    float pv = exp2f(s[nt][r] - mnew[r]);
                    rs[r] += pv;
                    sP[wave][(quad * 4 + r) * 72 + nt * 16 + c] = f2bf(pv);
                }
#pragma unroll
            for (int r = 0; r < 4; r++) {
                float v = rs[r];
                v += __shfl_xor(v, 1);
                v += __shfl_xor(v, 2);
                v += __shfl_xor(v, 4);
                v += __shfl_xor(v, 8);
                ls[r] = ls[r] * alpha[r] + v;
            }
#pragma unroll
            for (int dt = 0; dt < 8; dt++)
#pragma unroll
                for (int r = 0; r < 4; r++) oa[dt][r] *= alpha[r];

            __asm__ volatile("s_waitcnt lgkmcnt(0)" ::: "memory");  // drain wave-private sP writes

            // O += P V
#pragma unroll
            for (int k2 = 0; k2 < 2; k2++) {
                bf16x8 pf = *(const bf16x8*)&sP[wave][c * 72 + k2 * 32 + quad * 8];
#pragma unroll
                for (int dt = 0; dt < 8; dt++) {
                    int ld = dt * 16 + c;
                    int gc = k2 * 4 + quad;
                    int pch = (gc ^ ld) & 7;
                    bf16x8 vf = *(const bf16x8*)&sVt[ld * 64 + pch * 8];
                    oa[dt] = __builtin_amdgcn_mfma_f32_16x16x32_bf16(pf, vf, oa[dt], 0, 0, 0);
                }
            }
        }

        // epilogue
#pragma unroll
        for (int r = 0; r < 4; r++) {
            float inv = 1.f / ls[r];
            int row = q0 + wave * 16 + quad * 4 + r;
#pragma unroll
            for (int dt = 0; dt < 8; dt++)
                O[(size_t)row * DIM + h * HD + dt * 16 + c] = f2bf(oa[dt][r] * inv);
        }
    }
}

extern "C" void kernel_launch(void* const* d_in, const int* in_sizes, int n_in,
                              void* d_out, int out_size, void* d_ws, size_t ws_size,
                              hipStream_t stream) {
    const float* x     = (const float*)d_in[0];
    const float* freqs = (const float*)d_in[2];
    const float* wq    = (const float*)d_in[4];
    const float* wk    = (const float*)d_in[5];
    const float* wv    = (const float*)d_in[6];
    const float* wo    = (const float*)d_in[7];
    float* out = (float*)d_out;

    ushort* xb    = (ushort*)d_ws;
    ushort* wqb   = xb    + (size_t)SEQ * DIM;
    ushort* wkb   = wqb   + (size_t)DIM * DIM;
    ushort* wvb   = wkb   + (size_t)DIM * DIM;
    ushort* wob   = wvb   + (size_t)DIM * DIM;
    ushort* qbuf  = wob   + (size_t)DIM * DIM;
    ushort* kbuf  = qbuf  + (size_t)SEQ * DIM;
    ushort* vtbuf = kbuf  + (size_t)SEQ * DIM;   // [DIM][SEQ] = V^T per head
    ushort* obuf  = vtbuf + (size_t)SEQ * DIM;

    const int n4tot = (SEQ * DIM + 4 * DIM * DIM) / 4;
    conv_all<<<n4tot / 256, 256, 0, stream>>>(x, wq, wk, wv, wo, xb, wqb, wkb, wvb, wob);

    gemm_qkv<<<dim3(3 * DIM / 128, SEQ / 128), 256, 0, stream>>>(
        xb, wqb, wkb, wvb, qbuf, kbuf, vtbuf, freqs);

    flash_kernel<<<dim3(NH * SEQ / 128), 256, 0, stream>>>(qbuf, kbuf, vtbuf, obuf);

    gemm_f32out<<<dim3(DIM / 128, SEQ / 128), 256, 0, stream>>>(obuf, wob, out, SEQ, DIM, DIM);
}

// Round 3
// 804.819 us; speedup vs baseline: 1.3081x; 1.0090x over previous
//
#include <hip/hip_runtime.h>

#define DIM 4096
#define SEQ 2048
#define NH 32
#define HD 128

typedef __bf16 bf16x8 __attribute__((ext_vector_type(8)));
typedef float f32x4 __attribute__((ext_vector_type(4)));

// log2(e) / sqrt(HD): folded into Q so softmax runs in exp2 domain
#define QSCALE 0.12751649736765598f

__device__ inline ushort f2bf(float f) {
    union { float f; unsigned u; } v; v.f = f;
    unsigned r = v.u + 0x7fffu + ((v.u >> 16) & 1u);
    return (ushort)(r >> 16);
}

// ---------------- fused fp32 -> bf16 convert for x + all 4 weights ----------------
__global__ void conv_all(const float* __restrict__ x,  const float* __restrict__ wq,
                         const float* __restrict__ wk, const float* __restrict__ wv,
                         const float* __restrict__ wo,
                         ushort* __restrict__ xb,  ushort* __restrict__ wqb,
                         ushort* __restrict__ wkb, ushort* __restrict__ wvb,
                         ushort* __restrict__ wob) {
    int i = blockIdx.x * 256 + threadIdx.x;   // over (SEQ*DIM + 4*DIM*DIM)/4 float4s
    const float* src; ushort* dst; int off;
    const int n4x = (SEQ * DIM) / 4;          // 2^21
    if (i < n4x) { src = x; dst = xb; off = i; }
    else {
        int j = i - n4x;
        int w = j >> 22;                      // DIM*DIM/4 = 2^22
        off = j & ((1 << 22) - 1);
        src = (w == 0) ? wq : (w == 1) ? wk : (w == 2) ? wv : wo;
        dst = (w == 0) ? wqb : (w == 1) ? wkb : (w == 2) ? wvb : wob;
    }
    float4 v = ((const float4*)src)[off];
    ushort4 o;
    o.x = f2bf(v.x); o.y = f2bf(v.y); o.z = f2bf(v.z); o.w = f2bf(v.w);
    ((ushort4*)dst)[off] = o;
}

// ---------------- fused QKV GEMM, rotary folded into epilogue ----------------
// C[m][n] = sum_k A[m][k] * B[n][k].  1-D grid 1536, XCD-aware remap:
// XCD x = bi&7 owns m-rows {2x, 2x+1} (A strip 2MB stays L2-resident) and sweeps
// n with each B-tile used twice back-to-back (immediate L2 reuse, L3 cross-XCD).
// LDS chunk swizzle: row r stores global chunk g at pos (g + (r>>1))&3 ->
// b128 fragment reads spread start-banks to 2-way aliasing (free).
__global__ __launch_bounds__(256)
void gemm_qkv(const ushort* __restrict__ A,
              const ushort* __restrict__ Bq, const ushort* __restrict__ Bk,
              const ushort* __restrict__ Bv,
              ushort* __restrict__ qout, ushort* __restrict__ kout,
              ushort* __restrict__ vt, const float* __restrict__ freqs) {
    __shared__ __align__(16) ushort sA[128 * 32];
    __shared__ __align__(16) ushort sB[128 * 32];
    const int bi = blockIdx.x;
    const int jj = bi >> 3;
    const int mblk = (bi & 7) * 2 + (jj & 1);   // 0..15
    const int nblk = jj >> 1;                   // 0..95
    const int wsel = nblk >> 5;                 // 0=q 1=k 2=v
    const int nloc = (nblk & 31) * 128;
    const int m0 = mblk * 128;
    const int tid = threadIdx.x;
    const int wave = tid >> 6, lane = tid & 63;
    const int quad = lane >> 4, c = lane & 15;
    const int wm = (wave >> 1) * 64, wn = (wave & 1) * 64;
    const ushort* B = (wsel == 0) ? Bq : (wsel == 1) ? Bk : Bv;
    const int K = DIM;

    const f32x4 vzero = {0.f, 0.f, 0.f, 0.f};
    f32x4 acc[4][4];
#pragma unroll
    for (int i = 0; i < 4; i++)
#pragma unroll
        for (int j = 0; j < 4; j++) acc[i][j] = vzero;

    const int srow = lane >> 2;                     // 0..15 (row within group)
    const int sg   = ((lane & 3) - (srow >> 1)) & 3;// source chunk for this pos
    const int scol = sg * 8;
    const int rpos = (quad + ((c >> 1) & 3)) & 3;   // read position of chunk `quad`
    const size_t arow0 = (size_t)(m0 + wave * 32) * K;
    const size_t brow0 = (size_t)(nloc + wave * 32) * K;

    for (int k0 = 0; k0 < K; k0 += 32) {
#pragma unroll
        for (int j = 0; j < 2; j++) {
            __builtin_amdgcn_global_load_lds(
                (const __attribute__((address_space(1))) void*)(A + arow0 + (size_t)(j * 16 + srow) * K + k0 + scol),
                (__attribute__((address_space(3))) void*)(&sA[(wave * 32 + j * 16) * 32]), 16, 0, 0);
            __builtin_amdgcn_global_load_lds(
                (const __attribute__((address_space(1))) void*)(B + brow0 + (size_t)(j * 16 + srow) * K + k0 + scol),
                (__attribute__((address_space(3))) void*)(&sB[(wave * 32 + j * 16) * 32]), 16, 0, 0);
        }
        __syncthreads();
        bf16x8 af[4], bfr[4];
#pragma unroll
        for (int t = 0; t < 4; t++) {
            af[t]  = *(const bf16x8*)&sA[(wm + t * 16 + c) * 32 + rpos * 8];
            bfr[t] = *(const bf16x8*)&sB[(wn + t * 16 + c) * 32 + rpos * 8];
        }
#pragma unroll
        for (int mt = 0; mt < 4; mt++)
#pragma unroll
            for (int nt = 0; nt < 4; nt++)
                acc[mt][nt] = __builtin_amdgcn_mfma_f32_16x16x32_bf16(af[mt], bfr[nt], acc[mt][nt], 0, 0, 0);
        __syncthreads();
    }

    if (wsel < 2) {
        ushort* Cw = wsel ? kout : qout;
        const float qs = wsel ? 1.0f : QSCALE;
#pragma unroll
        for (int mt = 0; mt < 4; mt++) {
#pragma unroll
            for (int nt = 0; nt < 4; nt++) {
                int colg = nloc + wn + nt * 16 + c;
                int dh = (colg & 127) >> 1;
#pragma unroll
                for (int r = 0; r < 4; r++) {
                    int row = m0 + wm + mt * 16 + quad * 4 + r;
                    float2 f2 = ((const float2*)freqs)[row * 64 + dh];
                    float f = (f2.x + ((c & 1) ? f2.y : -f2.y)) * qs;
                    Cw[(size_t)row * DIM + colg] = f2bf(acc[mt][nt][r] * f);
                }
            }
        }
    } else {
        // V: write transposed vt[cv][seq]; lane holds 4 consecutive seq rows
#pragma unroll
        for (int mt = 0; mt < 4; mt++) {
#pragma unroll
            for (int nt = 0; nt < 4; nt++) {
                int cv = nloc + wn + nt * 16 + c;
                int row0 = m0 + wm + mt * 16 + quad * 4;
                ushort4 o;
                o.x = f2bf(acc[mt][nt][0]); o.y = f2bf(acc[mt][nt][1]);
                o.z = f2bf(acc[mt][nt][2]); o.w = f2bf(acc[mt][nt][3]);
                *(ushort4*)&vt[(size_t)cv * SEQ + row0] = o;
            }
        }
    }
}

// ---------------- plain bf16 GEMM with fp32 output (final projection) ----------------
// 1-D grid 512, same XCD remap (m-rows 16, n-tiles 32) and LDS swizzle.
__global__ __launch_bounds__(256)
void gemm_f32out(const ushort* __restrict__ A, const ushort* __restrict__ B,
                 float* __restrict__ C, int M, int N, int K) {
    __shared__ __align__(16) ushort sA[128 * 32];
    __shared__ __align__(16) ushort sB[128 * 32];
    const int bi = blockIdx.x;
    const int jj = bi >> 3;
    const int mblk = (bi & 7) * 2 + (jj & 1);   // 0..15
    const int nblk = jj >> 1;                   // 0..31
    const int m0 = mblk * 128, n0 = nblk * 128;
    const int tid = threadIdx.x;
    const int wave = tid >> 6, lane = tid & 63;
    const int quad = lane >> 4, c = lane & 15;
    const int wm = (wave >> 1) * 64, wn = (wave & 1) * 64;

    const f32x4 vzero = {0.f, 0.f, 0.f, 0.f};
    f32x4 acc[4][4];
#pragma unroll
    for (int i = 0; i < 4; i++)
#pragma unroll
        for (int j = 0; j < 4; j++) acc[i][j] = vzero;

    const int srow = lane >> 2;
    const int sg   = ((lane & 3) - (srow >> 1)) & 3;
    const int scol = sg * 8;
    const int rpos = (quad + ((c >> 1) & 3)) & 3;
    const size_t arow0 = (size_t)(m0 + wave * 32) * K;
    const size_t brow0 = (size_t)(n0 + wave * 32) * K;

    for (int k0 = 0; k0 < K; k0 += 32) {
#pragma unroll
        for (int j = 0; j < 2; j++) {
            __builtin_amdgcn_global_load_lds(
                (const __attribute__((address_space(1))) void*)(A + arow0 + (size_t)(j * 16 + srow) * K + k0 + scol),
                (__attribute__((address_space(3))) void*)(&sA[(wave * 32 + j * 16) * 32]), 16, 0, 0);
            __builtin_amdgcn_global_load_lds(
                (const __attribute__((address_space(1))) void*)(B + brow0 + (size_t)(j * 16 + srow) * K + k0 + scol),
                (__attribute__((address_space(3))) void*)(&sB[(wave * 32 + j * 16) * 32]), 16, 0, 0);
        }
        __syncthreads();
        bf16x8 af[4], bfr[4];
#pragma unroll
        for (int t = 0; t < 4; t++) {
            af[t]  = *(const bf16x8*)&sA[(wm + t * 16 + c) * 32 + rpos * 8];
            bfr[t] = *(const bf16x8*)&sB[(wn + t * 16 + c) * 32 + rpos * 8];
        }
#pragma unroll
        for (int mt = 0; mt < 4; mt++)
#pragma unroll
            for (int nt = 0; nt < 4; nt++)
                acc[mt][nt] = __builtin_amdgcn_mfma_f32_16x16x32_bf16(af[mt], bfr[nt], acc[mt][nt], 0, 0, 0);
        __syncthreads();
    }

#pragma unroll
    for (int mt = 0; mt < 4; mt++)
#pragma unroll
        for (int nt = 0; nt < 4; nt++)
#pragma unroll
            for (int r = 0; r < 4; r++) {
                int row = m0 + wm + mt * 16 + quad * 4 + r;
                int col = n0 + wn + nt * 16 + c;
                C[(size_t)row * N + col] = acc[mt][nt][r];
            }
}

// ---------------- flash attention (causal), balanced pairing + swizzled LDS ----------------
// 512 blocks: block handles head h = bi&31 and q-block pair {p, 31-p}, p = bi>>5
// -> exactly 33 K-tile iterations per block (perfect balance).
__global__ __launch_bounds__(256)
void flash_kernel(const ushort* __restrict__ Q, const ushort* __restrict__ K,
                  const ushort* __restrict__ Vt, ushort* __restrict__ O) {
    const int bi = blockIdx.x;
    const int h = bi & (NH - 1);
    const int p = bi >> 5;
    __shared__ __align__(16) ushort sK[64 * 128];
    __shared__ __align__(16) ushort sVt[128 * 64];
    __shared__ __align__(16) ushort sP[4][16 * 72];
    const int tid = threadIdx.x, wave = tid >> 6, lane = tid & 63;
    const int quad = lane >> 4, c = lane & 15;

    for (int pass = 0; pass < 2; pass++) {
        const int qb = pass ? (SEQ / 64 - 1 - p) : p;
        const int q0 = qb * 64;

        bf16x8 qf[4];
        {
            const ushort* Qp = Q + (size_t)(q0 + wave * 16 + c) * DIM + h * HD;
#pragma unroll
            for (int ks = 0; ks < 4; ks++) qf[ks] = *(const bf16x8*)(Qp + ks * 32 + quad * 8);
        }
        const f32x4 vzero = {0.f, 0.f, 0.f, 0.f};
        f32x4 oa[8];
#pragma unroll
        for (int dt = 0; dt < 8; dt++) oa[dt] = vzero;
        float ms[4], ls[4];
#pragma unroll
        for (int r = 0; r < 4; r++) { ms[r] = -1e30f; ls[r] = 0.f; }

        for (int kt = 0; kt <= qb; kt++) {
            __syncthreads();
            // stage K tile [64 keys][128 d]: wave covers 16 rows in 4 insts
#pragma unroll
            for (int i = 0; i < 4; i++) {
                int lr = wave * 16 + i * 4 + (lane >> 4);
                int ch = lane & 15;
                int g = (ch & 8) | ((ch ^ lr) & 7);
                __builtin_amdgcn_global_load_lds(
                    (const __attribute__((address_space(1))) void*)(K + (size_t)(kt * 64 + lr) * DIM + h * HD + g * 8),
                    (__attribute__((address_space(3))) void*)(&sK[(wave * 16 + i * 4) * 128]), 16, 0, 0);
            }
            // stage V^T tile [128 d][64 keys]: wave covers 32 rows in 4 insts
#pragma unroll
            for (int i = 0; i < 4; i++) {
                int ld = wave * 32 + i * 8 + (lane >> 3);
                int ch = lane & 7;
                int g = (ch ^ ld) & 7;
                __builtin_amdgcn_global_load_lds(
                    (const __attribute__((address_space(1))) void*)(Vt + (size_t)(h * HD + ld) * SEQ + kt * 64 + g * 8),
                    (__attribute__((address_space(3))) void*)(&sVt[(wave * 32 + i * 8) * 64]), 16, 0, 0);
            }
            __syncthreads();

            // S = Q K^T (Q pre-scaled by log2e/sqrt(HD))
            f32x4 s[4];
#pragma unroll
            for (int nt = 0; nt < 4; nt++) s[nt] = vzero;
#pragma unroll
            for (int ks = 0; ks < 4; ks++)
#pragma unroll
                for (int nt = 0; nt < 4; nt++) {
                    int lr = nt * 16 + c;
                    int gc = ks * 4 + quad;
                    int pch = (gc & 8) | ((gc ^ lr) & 7);
                    bf16x8 kf = *(const bf16x8*)&sK[lr * 128 + pch * 8];
                    s[nt] = __builtin_amdgcn_mfma_f32_16x16x32_bf16(qf[ks], kf, s[nt], 0, 0, 0);
                }

            if (kt == qb) {  // causal mask on the diagonal tile
#pragma unroll
                for (int nt = 0; nt < 4; nt++)
#pragma unroll
                    for (int r = 0; r < 4; r++) {
                        int keyg = nt * 16 + c;
                        int qg   = wave * 16 + quad * 4 + r;
                        if (keyg > qg) s[nt][r] = -1e30f;
                    }
            }

            // online softmax (exp2 domain)
            float mnew[4], alpha[4];
#pragma unroll
            for (int r = 0; r < 4; r++) {
                float v = fmaxf(fmaxf(s[0][r], s[1][r]), fmaxf(s[2][r], s[3][r]));
                v = fmaxf(v, __shfl_xor(v, 1));
                v = fmaxf(v, __shfl_xor(v, 2));
                v = fmaxf(v, __shfl_xor(v, 4));
                v = fmaxf(v, __shfl_xor(v, 8));
                mnew[r]  = fmaxf(ms[r], v);
                alpha[r] = exp2f(ms[r] - mnew[r]);
                ms[r]    = mnew[r];
            }
            float rs[4] = {0.f, 0.f, 0.f, 0.f};
#pragma unroll
            for (int nt = 0; nt < 4; nt++)
#pragma unroll
                for (int r = 0; r < 4; r++) {
                    float pv = exp2f(s[nt][r] - mnew[r]);
                    rs[r] += pv;
                    sP[wave][(quad * 4 + r) * 72 + nt * 16 + c] = f2bf(pv);
                }
#pragma unroll
            for (int r = 0; r < 4; r++) {
                float v = rs[r];
                v += __shfl_xor(v, 1);
                v += __shfl_xor(v, 2);
                v += __shfl_xor(v, 4);
                v += __shfl_xor(v, 8);
                ls[r] = ls[r] * alpha[r] + v;
            }
#pragma unroll
            for (int dt = 0; dt < 8; dt++)
#pragma unroll
                for (int r = 0; r < 4; r++) oa[dt][r] *= alpha[r];

            __asm__ volatile("s_waitcnt lgkmcnt(0)" ::: "memory");  // drain wave-private sP writes

            // O += P V
#pragma unroll
            for (int k2 = 0; k2 < 2; k2++) {
                bf16x8 pf = *(const bf16x8*)&sP[wave][c * 72 + k2 * 32 + quad * 8];
#pragma unroll
                for (int dt = 0; dt < 8; dt++) {
                    int ld = dt * 16 + c;
                    int gc = k2 * 4 + quad;
                    int pch = (gc ^ ld) & 7;
                    bf16x8 vf = *(const bf16x8*)&sVt[ld * 64 + pch * 8];
                    oa[dt] = __builtin_amdgcn_mfma_f32_16x16x32_bf16(pf, vf, oa[dt], 0, 0, 0);
                }
            }
        }

        // epilogue
#pragma unroll
        for (int r = 0; r < 4; r++) {
            float inv = 1.f / ls[r];
            int row = q0 + wave * 16 + quad * 4 + r;
#pragma unroll
            for (int dt = 0; dt < 8; dt++)
                O[(size_t)row * DIM + h * HD + dt * 16 + c] = f2bf(oa[dt][r] * inv);
        }
    }
}

extern "C" void kernel_launch(void* const* d_in, const int* in_sizes, int n_in,
                              void* d_out, int out_size, void* d_ws, size_t ws_size,
                              hipStream_t stream) {
    const float* x     = (const float*)d_in[0];
    const float* freqs = (const float*)d_in[2];
    const float* wq    = (const float*)d_in[4];
    const float* wk    = (const float*)d_in[5];
    const float* wv    = (const float*)d_in[6];
    const float* wo    = (const float*)d_in[7];
    float* out = (float*)d_out;

    ushort* xb    = (ushort*)d_ws;
    ushort* wqb   = xb    + (size_t)SEQ * DIM;
    ushort* wkb   = wqb   + (size_t)DIM * DIM;
    ushort* wvb   = wkb   + (size_t)DIM * DIM;
    ushort* wob   = wvb   + (size_t)DIM * DIM;
    ushort* qbuf  = wob   + (size_t)DIM * DIM;
    ushort* kbuf  = qbuf  + (size_t)SEQ * DIM;
    ushort* vtbuf = kbuf  + (size_t)SEQ * DIM;   // [DIM][SEQ] = V^T per head
    ushort* obuf  = vtbuf + (size_t)SEQ * DIM;

    const int n4tot = (SEQ * DIM + 4 * DIM * DIM) / 4;
    conv_all<<<n4tot / 256, 256, 0, stream>>>(x, wq, wk, wv, wo, xb, wqb, wkb, wvb, wob);

    gemm_qkv<<<dim3(3 * DIM / 128 * SEQ / 128), 256, 0, stream>>>(
        xb, wqb, wkb, wvb, qbuf, kbuf, vtbuf, freqs);

    flash_kernel<<<dim3(NH * SEQ / 128), 256, 0, stream>>>(qbuf, kbuf, vtbuf, obuf);

    gemm_f32out<<<dim3(DIM / 128 * SEQ / 128), 256, 0, stream>>>(obuf, wob, out, SEQ, DIM, DIM);
}

// Round 4
// 765.028 us; speedup vs baseline: 1.3761x; 1.0520x over previous
//
#include <hip/hip_runtime.h>

#define DIM 4096
#define SEQ 2048
#define NH 32
#define HD 128

typedef __bf16 bf16x8 __attribute__((ext_vector_type(8)));
typedef float f32x4 __attribute__((ext_vector_type(4)));

// log2(e) / sqrt(HD): folded into Q so softmax runs in exp2 domain
#define QSCALE 0.12751649736765598f

__device__ inline ushort f2bf(float f) {
    union { float f; unsigned u; } v; v.f = f;
    unsigned r = v.u + 0x7fffu + ((v.u >> 16) & 1u);
    return (ushort)(r >> 16);
}

// ---------------- fused fp32 -> bf16 convert for x + all 4 weights ----------------
__global__ void conv_all(const float* __restrict__ x,  const float* __restrict__ wq,
                         const float* __restrict__ wk, const float* __restrict__ wv,
                         const float* __restrict__ wo,
                         ushort* __restrict__ xb,  ushort* __restrict__ wqb,
                         ushort* __restrict__ wkb, ushort* __restrict__ wvb,
                         ushort* __restrict__ wob) {
    int i = blockIdx.x * 256 + threadIdx.x;   // over (SEQ*DIM + 4*DIM*DIM)/4 float4s
    const float* src; ushort* dst; int off;
    const int n4x = (SEQ * DIM) / 4;          // 2^21
    if (i < n4x) { src = x; dst = xb; off = i; }
    else {
        int j = i - n4x;
        int w = j >> 22;                      // DIM*DIM/4 = 2^22
        off = j & ((1 << 22) - 1);
        src = (w == 0) ? wq : (w == 1) ? wk : (w == 2) ? wv : wo;
        dst = (w == 0) ? wqb : (w == 1) ? wkb : (w == 2) ? wvb : wob;
    }
    float4 v = ((const float4*)src)[off];
    ushort4 o;
    o.x = f2bf(v.x); o.y = f2bf(v.y); o.z = f2bf(v.z); o.w = f2bf(v.w);
    ((ushort4*)dst)[off] = o;
}

// ---------------- fused QKV GEMM, BK=64, rotary folded into epilogue ----------------
// C[m][n] = sum_k A[m][k] * B[n][k].  Grid 1536, XCD n-partition:
// XCD x = bi&7 exclusively owns 12 n-tiles (B fetched from HBM once, per-XCD
// L2 window ~6MB); m sweeps fastest within each n-tile (A 16MB stays L3-hot).
// LDS: rows of 64 elems = 8 chunks of 16B; row r stores global chunk g at pos
// g^(r&7) -> b128 fragment reads are 2-way bank-aliased (free), DMA dest is
// wave-uniform base + lane*16 (required by global_load_lds).
__global__ __launch_bounds__(256)
void gemm_qkv(const ushort* __restrict__ A,
              const ushort* __restrict__ Bq, const ushort* __restrict__ Bk,
              const ushort* __restrict__ Bv,
              ushort* __restrict__ qout, ushort* __restrict__ kout,
              ushort* __restrict__ vt, const float* __restrict__ freqs) {
    __shared__ __align__(16) ushort sA[128 * 64];
    __shared__ __align__(16) ushort sB[128 * 64];
    const int bi = blockIdx.x;
    const int x = bi & 7;                    // XCD (round-robin dispatch)
    const int l = bi >> 3;                   // 0..191 within XCD
    const int mblk = l & 15;
    const int nblk = x * 12 + (l >> 4);      // 0..95, exclusive per XCD
    const int wsel = nblk >> 5;              // 0=q 1=k 2=v
    const int nloc = (nblk & 31) * 128;
    const int m0 = mblk * 128;
    const int tid = threadIdx.x;
    const int wave = tid >> 6, lane = tid & 63;
    const int quad = lane >> 4, c = lane & 15;
    const int wm = (wave >> 1) * 64, wn = (wave & 1) * 64;
    const ushort* B = (wsel == 0) ? Bq : (wsel == 1) ? Bk : Bv;
    const int K = DIM;

    const f32x4 vzero = {0.f, 0.f, 0.f, 0.f};
    f32x4 acc[4][4];
#pragma unroll
    for (int i = 0; i < 4; i++)
#pragma unroll
        for (int j = 0; j < 4; j++) acc[i][j] = vzero;

    // staging geometry: wave covers 8 rows x 8 chunks per inst
    const int srow8 = lane >> 3;             // row within 8-row group
    const int sg    = (lane & 7) ^ srow8;    // source chunk for this LDS pos
    const int scol  = sg * 8;
    // fragment read chunk positions (row&7 == c&7 for all tiles)
    const int rp0 = ((0 * 4 + quad) ^ (c & 7)) * 8;
    const int rp1 = ((1 * 4 + quad) ^ (c & 7)) * 8;
    const size_t arow0 = (size_t)(m0 + wave * 32) * K;
    const size_t brow0 = (size_t)(nloc + wave * 32) * K;

    for (int k0 = 0; k0 < K; k0 += 64) {
#pragma unroll
        for (int i = 0; i < 4; i++) {
            __builtin_amdgcn_global_load_lds(
                (const __attribute__((address_space(1))) void*)(A + arow0 + (size_t)(i * 8 + srow8) * K + k0 + scol),
                (__attribute__((address_space(3))) void*)(&sA[(wave * 32 + i * 8) * 64]), 16, 0, 0);
            __builtin_amdgcn_global_load_lds(
                (const __attribute__((address_space(1))) void*)(B + brow0 + (size_t)(i * 8 + srow8) * K + k0 + scol),
                (__attribute__((address_space(3))) void*)(&sB[(wave * 32 + i * 8) * 64]), 16, 0, 0);
        }
        __syncthreads();
#pragma unroll
        for (int kk = 0; kk < 2; kk++) {
            const int rp = kk ? rp1 : rp0;
            bf16x8 af[4], bfr[4];
#pragma unroll
            for (int t = 0; t < 4; t++) {
                af[t]  = *(const bf16x8*)&sA[(wm + t * 16 + c) * 64 + rp];
                bfr[t] = *(const bf16x8*)&sB[(wn + t * 16 + c) * 64 + rp];
            }
#pragma unroll
            for (int mt = 0; mt < 4; mt++)
#pragma unroll
                for (int nt = 0; nt < 4; nt++)
                    acc[mt][nt] = __builtin_amdgcn_mfma_f32_16x16x32_bf16(af[mt], bfr[nt], acc[mt][nt], 0, 0, 0);
        }
        __syncthreads();
    }

    if (wsel < 2) {
        ushort* Cw = wsel ? kout : qout;
        const float qs = wsel ? 1.0f : QSCALE;
#pragma unroll
        for (int mt = 0; mt < 4; mt++) {
#pragma unroll
            for (int nt = 0; nt < 4; nt++) {
                int colg = nloc + wn + nt * 16 + c;
                int dh = (colg & 127) >> 1;
#pragma unroll
                for (int r = 0; r < 4; r++) {
                    int row = m0 + wm + mt * 16 + quad * 4 + r;
                    float2 f2 = ((const float2*)freqs)[row * 64 + dh];
                    float f = (f2.x + ((c & 1) ? f2.y : -f2.y)) * qs;
                    Cw[(size_t)row * DIM + colg] = f2bf(acc[mt][nt][r] * f);
                }
            }
        }
    } else {
        // V: write transposed vt[cv][seq]; lane holds 4 consecutive seq rows
#pragma unroll
        for (int mt = 0; mt < 4; mt++) {
#pragma unroll
            for (int nt = 0; nt < 4; nt++) {
                int cv = nloc + wn + nt * 16 + c;
                int row0 = m0 + wm + mt * 16 + quad * 4;
                ushort4 o;
                o.x = f2bf(acc[mt][nt][0]); o.y = f2bf(acc[mt][nt][1]);
                o.z = f2bf(acc[mt][nt][2]); o.w = f2bf(acc[mt][nt][3]);
                *(ushort4*)&vt[(size_t)cv * SEQ + row0] = o;
            }
        }
    }
}

// ---------------- bf16 GEMM, BK=64, fp32 output (final projection) ----------------
// Grid 512, XCD n-partition: XCD owns 4 n-tiles, m sweeps fastest.
__global__ __launch_bounds__(256)
void gemm_f32out(const ushort* __restrict__ A, const ushort* __restrict__ B,
                 float* __restrict__ C, int M, int N, int K) {
    __shared__ __align__(16) ushort sA[128 * 64];
    __shared__ __align__(16) ushort sB[128 * 64];
    const int bi = blockIdx.x;
    const int x = bi & 7;
    const int l = bi >> 3;                   // 0..63
    const int mblk = l & 15;
    const int nblk = x * 4 + (l >> 4);       // 0..31
    const int m0 = mblk * 128, n0 = nblk * 128;
    const int tid = threadIdx.x;
    const int wave = tid >> 6, lane = tid & 63;
    const int quad = lane >> 4, c = lane & 15;
    const int wm = (wave >> 1) * 64, wn = (wave & 1) * 64;

    const f32x4 vzero = {0.f, 0.f, 0.f, 0.f};
    f32x4 acc[4][4];
#pragma unroll
    for (int i = 0; i < 4; i++)
#pragma unroll
        for (int j = 0; j < 4; j++) acc[i][j] = vzero;

    const int srow8 = lane >> 3;
    const int sg    = (lane & 7) ^ srow8;
    const int scol  = sg * 8;
    const int rp0 = ((0 * 4 + quad) ^ (c & 7)) * 8;
    const int rp1 = ((1 * 4 + quad) ^ (c & 7)) * 8;
    const size_t arow0 = (size_t)(m0 + wave * 32) * K;
    const size_t brow0 = (size_t)(n0 + wave * 32) * K;

    for (int k0 = 0; k0 < K; k0 += 64) {
#pragma unroll
        for (int i = 0; i < 4; i++) {
            __builtin_amdgcn_global_load_lds(
                (const __attribute__((address_space(1))) void*)(A + arow0 + (size_t)(i * 8 + srow8) * K + k0 + scol),
                (__attribute__((address_space(3))) void*)(&sA[(wave * 32 + i * 8) * 64]), 16, 0, 0);
            __builtin_amdgcn_global_load_lds(
                (const __attribute__((address_space(1))) void*)(B + brow0 + (size_t)(i * 8 + srow8) * K + k0 + scol),
                (__attribute__((address_space(3))) void*)(&sB[(wave * 32 + i * 8) * 64]), 16, 0, 0);
        }
        __syncthreads();
#pragma unroll
        for (int kk = 0; kk < 2; kk++) {
            const int rp = kk ? rp1 : rp0;
            bf16x8 af[4], bfr[4];
#pragma unroll
            for (int t = 0; t < 4; t++) {
                af[t]  = *(const bf16x8*)&sA[(wm + t * 16 + c) * 64 + rp];
                bfr[t] = *(const bf16x8*)&sB[(wn + t * 16 + c) * 64 + rp];
            }
#pragma unroll
            for (int mt = 0; mt < 4; mt++)
#pragma unroll
                for (int nt = 0; nt < 4; nt++)
                    acc[mt][nt] = __builtin_amdgcn_mfma_f32_16x16x32_bf16(af[mt], bfr[nt], acc[mt][nt], 0, 0, 0);
        }
        __syncthreads();
    }

#pragma unroll
    for (int mt = 0; mt < 4; mt++)
#pragma unroll
        for (int nt = 0; nt < 4; nt++)
#pragma unroll
            for (int r = 0; r < 4; r++) {
                int row = m0 + wm + mt * 16 + quad * 4 + r;
                int col = n0 + wn + nt * 16 + c;
                C[(size_t)row * N + col] = acc[mt][nt][r];
            }
}

// ---------------- flash attention (causal), balanced pairing + swizzled LDS ----------------
// 512 blocks: block handles head h = bi&31 and q-block pair {p, 31-p}, p = bi>>5
// -> exactly 33 K-tile iterations per block (perfect balance).
__global__ __launch_bounds__(256)
void flash_kernel(const ushort* __restrict__ Q, const ushort* __restrict__ K,
                  const ushort* __restrict__ Vt, ushort* __restrict__ O) {
    const int bi = blockIdx.x;
    const int h = bi & (NH - 1);
    const int p = bi >> 5;
    __shared__ __align__(16) ushort sK[64 * 128];
    __shared__ __align__(16) ushort sVt[128 * 64];
    __shared__ __align__(16) ushort sP[4][16 * 72];
    const int tid = threadIdx.x, wave = tid >> 6, lane = tid & 63;
    const int quad = lane >> 4, c = lane & 15;

    for (int pass = 0; pass < 2; pass++) {
        const int qb = pass ? (SEQ / 64 - 1 - p) : p;
        const int q0 = qb * 64;

        bf16x8 qf[4];
        {
            const ushort* Qp = Q + (size_t)(q0 + wave * 16 + c) * DIM + h * HD;
#pragma unroll
            for (int ks = 0; ks < 4; ks++) qf[ks] = *(const bf16x8*)(Qp + ks * 32 + quad * 8);
        }
        const f32x4 vzero = {0.f, 0.f, 0.f, 0.f};
        f32x4 oa[8];
#pragma unroll
        for (int dt = 0; dt < 8; dt++) oa[dt] = vzero;
        float ms[4], ls[4];
#pragma unroll
        for (int r = 0; r < 4; r++) { ms[r] = -1e30f; ls[r] = 0.f; }

        for (int kt = 0; kt <= qb; kt++) {
            __syncthreads();
            // stage K tile [64 keys][128 d]: wave covers 16 rows in 4 insts
#pragma unroll
            for (int i = 0; i < 4; i++) {
                int lr = wave * 16 + i * 4 + (lane >> 4);
                int ch = lane & 15;
                int g = (ch & 8) | ((ch ^ lr) & 7);
                __builtin_amdgcn_global_load_lds(
                    (const __attribute__((address_space(1))) void*)(K + (size_t)(kt * 64 + lr) * DIM + h * HD + g * 8),
                    (__attribute__((address_space(3))) void*)(&sK[(wave * 16 + i * 4) * 128]), 16, 0, 0);
            }
            // stage V^T tile [128 d][64 keys]: wave covers 32 rows in 4 insts
#pragma unroll
            for (int i = 0; i < 4; i++) {
                int ld = wave * 32 + i * 8 + (lane >> 3);
                int ch = lane & 7;
                int g = (ch ^ ld) & 7;
                __builtin_amdgcn_global_load_lds(
                    (const __attribute__((address_space(1))) void*)(Vt + (size_t)(h * HD + ld) * SEQ + kt * 64 + g * 8),
                    (__attribute__((address_space(3))) void*)(&sVt[(wave * 32 + i * 8) * 64]), 16, 0, 0);
            }
            __syncthreads();

            // S = Q K^T (Q pre-scaled by log2e/sqrt(HD))
            f32x4 s[4];
#pragma unroll
            for (int nt = 0; nt < 4; nt++) s[nt] = vzero;
#pragma unroll
            for (int ks = 0; ks < 4; ks++)
#pragma unroll
                for (int nt = 0; nt < 4; nt++) {
                    int lr = nt * 16 + c;
                    int gc = ks * 4 + quad;
                    int pch = (gc & 8) | ((gc ^ lr) & 7);
                    bf16x8 kf = *(const bf16x8*)&sK[lr * 128 + pch * 8];
                    s[nt] = __builtin_amdgcn_mfma_f32_16x16x32_bf16(qf[ks], kf, s[nt], 0, 0, 0);
                }

            if (kt == qb) {  // causal mask on the diagonal tile
#pragma unroll
                for (int nt = 0; nt < 4; nt++)
#pragma unroll
                    for (int r = 0; r < 4; r++) {
                        int keyg = nt * 16 + c;
                        int qg   = wave * 16 + quad * 4 + r;
                        if (keyg > qg) s[nt][r] = -1e30f;
                    }
            }

            // online softmax (exp2 domain)
            float mnew[4], alpha[4];
#pragma unroll
            for (int r = 0; r < 4; r++) {
                float v = fmaxf(fmaxf(s[0][r], s[1][r]), fmaxf(s[2][r], s[3][r]));
                v = fmaxf(v, __shfl_xor(v, 1));
                v = fmaxf(v, __shfl_xor(v, 2));
                v = fmaxf(v, __shfl_xor(v, 4));
                v = fmaxf(v, __shfl_xor(v, 8));
                mnew[r]  = fmaxf(ms[r], v);
                alpha[r] = exp2f(ms[r] - mnew[r]);
                ms[r]    = mnew[r];
            }
            float rs[4] = {0.f, 0.f, 0.f, 0.f};
#pragma unroll
            for (int nt = 0; nt < 4; nt++)
#pragma unroll
                for (int r = 0; r < 4; r++) {
                    float pv = exp2f(s[nt][r] - mnew[r]);
                    rs[r] += pv;
                    sP[wave][(quad * 4 + r) * 72 + nt * 16 + c] = f2bf(pv);
                }
#pragma unroll
            for (int r = 0; r < 4; r++) {
                float v = rs[r];
                v += __shfl_xor(v, 1);
                v += __shfl_xor(v, 2);
                v += __shfl_xor(v, 4);
                v += __shfl_xor(v, 8);
                ls[r] = ls[r] * alpha[r] + v;
            }
#pragma unroll
            for (int dt = 0; dt < 8; dt++)
#pragma unroll
                for (int r = 0; r < 4; r++) oa[dt][r] *= alpha[r];

            __asm__ volatile("s_waitcnt lgkmcnt(0)" ::: "memory");  // drain wave-private sP writes

            // O += P V
#pragma unroll
            for (int k2 = 0; k2 < 2; k2++) {
                bf16x8 pf = *(const bf16x8*)&sP[wave][c * 72 + k2 * 32 + quad * 8];
#pragma unroll
                for (int dt = 0; dt < 8; dt++) {
                    int ld = dt * 16 + c;
                    int gc = k2 * 4 + quad;
                    int pch = (gc ^ ld) & 7;
                    bf16x8 vf = *(const bf16x8*)&sVt[ld * 64 + pch * 8];
                    oa[dt] = __builtin_amdgcn_mfma_f32_16x16x32_bf16(pf, vf, oa[dt], 0, 0, 0);
                }
            }
        }

        // epilogue
#pragma unroll
        for (int r = 0; r < 4; r++) {
            float inv = 1.f / ls[r];
            int row = q0 + wave * 16 + quad * 4 + r;
#pragma unroll
            for (int dt = 0; dt < 8; dt++)
                O[(size_t)row * DIM + h * HD + dt * 16 + c] = f2bf(oa[dt][r] * inv);
        }
    }
}

extern "C" void kernel_launch(void* const* d_in, const int* in_sizes, int n_in,
                              void* d_out, int out_size, void* d_ws, size_t ws_size,
                              hipStream_t stream) {
    const float* x     = (const float*)d_in[0];
    const float* freqs = (const float*)d_in[2];
    const float* wq    = (const float*)d_in[4];
    const float* wk    = (const float*)d_in[5];
    const float* wv    = (const float*)d_in[6];
    const float* wo    = (const float*)d_in[7];
    float* out = (float*)d_out;

    ushort* xb    = (ushort*)d_ws;
    ushort* wqb   = xb    + (size_t)SEQ * DIM;
    ushort* wkb   = wqb   + (size_t)DIM * DIM;
    ushort* wvb   = wkb   + (size_t)DIM * DIM;
    ushort* wob   = wvb   + (size_t)DIM * DIM;
    ushort* qbuf  = wob   + (size_t)DIM * DIM;
    ushort* kbuf  = qbuf  + (size_t)SEQ * DIM;
    ushort* vtbuf = kbuf  + (size_t)SEQ * DIM;   // [DIM][SEQ] = V^T per head
    ushort* obuf  = vtbuf + (size_t)SEQ * DIM;

    const int n4tot = (SEQ * DIM + 4 * DIM * DIM) / 4;
    conv_all<<<n4tot / 256, 256, 0, stream>>>(x, wq, wk, wv, wo, xb, wqb, wkb, wvb, wob);

    gemm_qkv<<<dim3(3 * DIM / 128 * SEQ / 128), 256, 0, stream>>>(
        xb, wqb, wkb, wvb, qbuf, kbuf, vtbuf, freqs);

    flash_kernel<<<dim3(NH * SEQ / 128), 256, 0, stream>>>(qbuf, kbuf, vtbuf, obuf);

    gemm_f32out<<<dim3(DIM / 128 * SEQ / 128), 256, 0, stream>>>(obuf, wob, out, SEQ, DIM, DIM);
}